// Round 1
// baseline (302.903 us; speedup 1.0000x reference)
//
#include <hip/hip_runtime.h>

#define BN_EPS 1e-5f

// ---------------- K0: zero the 6 stat accumulators ----------------
__global__ __launch_bounds__(64) void k_zero(float* ws) {
  if (threadIdx.x < 6) ws[threadIdx.x] = 0.f;
}

// ---------------- K1: per-channel sum / sumsq over x [512,3,128,128] ----------------
__global__ __launch_bounds__(256) void k_stats(const float4* __restrict__ x4,
                                               float* __restrict__ ws) {
  const int NV = 512 * 3 * 4096;  // float4 count
  float s0 = 0, s1 = 0, s2 = 0, q0 = 0, q1 = 0, q2 = 0;
  for (int v = blockIdx.x * 256 + threadIdx.x; v < NV; v += gridDim.x * 256) {
    float4 a = x4[v];
    int c = (v >> 12) % 3;  // 4096 float4 per channel-plane
    float ss = (a.x + a.y) + (a.z + a.w);
    float qq = (a.x * a.x + a.y * a.y) + (a.z * a.z + a.w * a.w);
    if (c == 0)      { s0 += ss; q0 += qq; }
    else if (c == 1) { s1 += ss; q1 += qq; }
    else             { s2 += ss; q2 += qq; }
  }
  #pragma unroll
  for (int off = 32; off; off >>= 1) {
    s0 += __shfl_down(s0, off); q0 += __shfl_down(q0, off);
    s1 += __shfl_down(s1, off); q1 += __shfl_down(q1, off);
    s2 += __shfl_down(s2, off); q2 += __shfl_down(q2, off);
  }
  __shared__ float red[4][6];
  int lane = threadIdx.x & 63, wv = threadIdx.x >> 6;
  if (lane == 0) {
    red[wv][0] = s0; red[wv][1] = s1; red[wv][2] = s2;
    red[wv][3] = q0; red[wv][4] = q1; red[wv][5] = q2;
  }
  __syncthreads();
  if (threadIdx.x == 0) {
    #pragma unroll
    for (int i = 0; i < 6; i++) {
      float t = red[0][i] + red[1][i] + red[2][i] + red[3][i];
      atomicAdd(&ws[i], t);
    }
  }
}

// ---------------- Kg: gather the 2028 live fc1 columns -> Wg [128][2028] ----------------
__global__ __launch_bounds__(256) void k_gather(const float* __restrict__ fc1_w,
                                                float* __restrict__ Wg) {
  int n = blockIdx.x;  // 128 rows
  for (int j = threadIdx.x; j < 2028; j += 256) {
    int c = j / 676;
    int rem = j - c * 676;
    int oy = rem / 26, ox = rem - oy * 26;
    int col = c * 4225 + ((5 * oy) >> 1) * 65 + ((5 * ox) >> 1);
    Wg[n * 2028 + j] = fc1_w[n * 12675 + col];
  }
}

// ---------------- K2: fused BN + conv1 + relu + 1x1 conv2 + relu + fc1 + fc2 + log_softmax ----------------
__global__ __launch_bounds__(256) void k_fused(
    const float* __restrict__ x,       // [512,3,128,128]
    const float* __restrict__ ws,      // sums at [0..5]
    const float* __restrict__ gamma, const float* __restrict__ beta,
    const float* __restrict__ w1, const float* __restrict__ b1,  // [3,3,5,5],[3]
    const float* __restrict__ w2, const float* __restrict__ b2,  // [3,3,5,5],[3]
    const float* __restrict__ Wg,      // [128][2028]
    const float* __restrict__ fc1_b,   // [128]
    const float* __restrict__ fc2_w, const float* __restrict__ fc2_b,  // [10,128],[10]
    float* __restrict__ out)           // [512,10]
{
  __shared__ float s_w1[225];          // [o][c][ky][kx] flat
  __shared__ float s_w2[3][3];
  __shared__ float s_scale[3], s_shift[3], s_b1[3], s_b2[3];
  __shared__ float s_feat[2028];       // [o][oy][ox]
  __shared__ float s_red[256];
  __shared__ float s_f[128];
  __shared__ float s_logits[10];
  __shared__ float s_lse;

  const int tid = threadIdx.x;
  const int b = blockIdx.x;

  if (tid < 225) s_w1[tid] = w1[tid];
  if (tid < 9) s_w2[tid / 3][tid % 3] = w2[tid * 25];  // w2[o][c][0][0]
  if (tid < 3) {
    const float N = 512.f * 128.f * 128.f;
    float mean = ws[tid] / N;
    float var = ws[3 + tid] / N - mean * mean;
    float sc = gamma[tid] * rsqrtf(var + BN_EPS);
    s_scale[tid] = sc;
    s_shift[tid] = beta[tid] - mean * sc;
    s_b1[tid] = b1[tid];
    s_b2[tid] = b2[tid];
  }
  __syncthreads();

  // ---- conv1 (k5 s5 on pad-1 BN'd input) + relu + 1x1 conv2 + relu -> s_feat ----
  const float* xb = x + (size_t)b * 49152;
  for (int pos = tid; pos < 676; pos += 256) {
    int oy = pos / 26, ox = pos - oy * 26;
    int r0 = 5 * oy - 1, c0 = 5 * ox - 1;
    float a0 = s_b1[0], a1 = s_b1[1], a2 = s_b1[2];
    #pragma unroll
    for (int c = 0; c < 3; c++) {
      const float* xc = xb + c * 16384;
      float sc = s_scale[c], sh = s_shift[c];
      #pragma unroll
      for (int ky = 0; ky < 5; ky++) {
        int r = r0 + ky;
        if (r < 0 || r > 127) continue;
        const float* xr = xc + r * 128;
        const float* wk = s_w1 + c * 25 + ky * 5;
        #pragma unroll
        for (int kx = 0; kx < 5; kx++) {
          int cc = c0 + kx;
          if (cc < 0 || cc > 127) continue;
          float v = xr[cc] * sc + sh;
          a0 += wk[kx] * v;
          a1 += wk[75 + kx] * v;
          a2 += wk[150 + kx] * v;
        }
      }
    }
    float h0 = fmaxf(a0, 0.f), h1 = fmaxf(a1, 0.f), h2 = fmaxf(a2, 0.f);
    #pragma unroll
    for (int o = 0; o < 3; o++) {
      float h = s_b2[o] + s_w2[o][0] * h0 + s_w2[o][1] * h1 + s_w2[o][2] * h2;
      s_feat[o * 676 + pos] = fmaxf(h, 0.f);
    }
  }
  __syncthreads();

  // ---- fc1: 2 threads per neuron, float4 weight stream ----
  {
    int n = tid & 127, h = tid >> 7;
    int j0 = h ? 1012 : 0;
    int nv = h ? 254 : 253;  // (2028-1012)/4 , 1012/4
    const float4* wrow = (const float4*)(Wg + n * 2028 + j0);
    float acc = 0.f;
    for (int v = 0; v < nv; v++) {
      float4 w = wrow[v];
      int j = j0 + 4 * v;
      acc += w.x * s_feat[j] + w.y * s_feat[j + 1] + w.z * s_feat[j + 2] + w.w * s_feat[j + 3];
    }
    s_red[tid] = acc;
  }
  __syncthreads();
  if (tid < 128) {
    float f = fc1_b[tid] + s_red[tid] + s_red[tid + 128];
    s_f[tid] = fmaxf(f, 0.f);
  }
  __syncthreads();

  // ---- fc2 + log_softmax ----
  if (tid < 10) {
    float acc = fc2_b[tid];
    const float* wr = fc2_w + tid * 128;
    #pragma unroll 8
    for (int n = 0; n < 128; n++) acc += wr[n] * s_f[n];
    s_logits[tid] = acc;
  }
  __syncthreads();
  if (tid == 0) {
    float m = s_logits[0];
    #pragma unroll
    for (int k = 1; k < 10; k++) m = fmaxf(m, s_logits[k]);
    float se = 0.f;
    #pragma unroll
    for (int k = 0; k < 10; k++) se += expf(s_logits[k] - m);
    s_lse = m + logf(se);
  }
  __syncthreads();
  if (tid < 10) out[b * 10 + tid] = s_logits[tid] - s_lse;
}

extern "C" void kernel_launch(void* const* d_in, const int* in_sizes, int n_in,
                              void* d_out, int out_size, void* d_ws, size_t ws_size,
                              hipStream_t stream) {
  const float* x      = (const float*)d_in[0];
  const float* gamma  = (const float*)d_in[1];
  const float* beta   = (const float*)d_in[2];
  const float* w1     = (const float*)d_in[3];
  const float* b1     = (const float*)d_in[4];
  const float* w2     = (const float*)d_in[5];
  const float* b2     = (const float*)d_in[6];
  const float* fc1_w  = (const float*)d_in[7];
  const float* fc1_b  = (const float*)d_in[8];
  const float* fc2_w  = (const float*)d_in[9];
  const float* fc2_b  = (const float*)d_in[10];
  float* out = (float*)d_out;
  float* wsf = (float*)d_ws;
  float* Wg = wsf + 16;  // 64B offset, 16B-aligned; needs 128*2028*4 ~= 1.04 MB

  k_zero<<<1, 64, 0, stream>>>(wsf);
  k_stats<<<2048, 256, 0, stream>>>((const float4*)x, wsf);
  k_gather<<<128, 256, 0, stream>>>(fc1_w, Wg);
  k_fused<<<512, 256, 0, stream>>>(x, wsf, gamma, beta, w1, b1, w2, b2,
                                   Wg, fc1_b, fc2_w, fc2_b, out);
}

// Round 2
// 222.708 us; speedup vs baseline: 1.3601x; 1.3601x over previous
//
#include <hip/hip_runtime.h>

#define BN_EPS 1e-5f

// ws float layout: [0..5] final stats | [64..1599] psum[1536] | [1664..3199] psq[1536]
// | [4096..] Wgt (507*512 floats = 1.04 MB, 16KB-aligned)

// ---------------- K1: per-plane sum / sumsq over x [512,3,128,128] ----------------
// One block per (b,c) plane: 1536 blocks, 4096 float4 each, no atomics.
__global__ __launch_bounds__(256) void k_stats(const float4* __restrict__ x4,
                                               float* __restrict__ psum,
                                               float* __restrict__ psq) {
  const int p = blockIdx.x;  // plane id: b*3 + c
  const float4* base = x4 + (size_t)p * 4096;
  float s = 0.f, q = 0.f;
  #pragma unroll
  for (int i = 0; i < 16; i++) {
    float4 a = base[i * 256 + threadIdx.x];
    s += (a.x + a.y) + (a.z + a.w);
    q += (a.x * a.x + a.y * a.y) + (a.z * a.z + a.w * a.w);
  }
  #pragma unroll
  for (int off = 32; off; off >>= 1) {
    s += __shfl_down(s, off);
    q += __shfl_down(q, off);
  }
  __shared__ float rs[4], rq[4];
  int lane = threadIdx.x & 63, w = threadIdx.x >> 6;
  if (lane == 0) { rs[w] = s; rq[w] = q; }
  __syncthreads();
  if (threadIdx.x == 0) {
    psum[p] = (rs[0] + rs[1]) + (rs[2] + rs[3]);
    psq[p]  = (rq[0] + rq[1]) + (rq[2] + rq[3]);
  }
}

// ---------------- K1b: fold 1536 partials -> 6 stats ----------------
// 6 waves; wave w = stat slot w (channel w%3, sum if w<3 else sumsq).
__global__ __launch_bounds__(384) void k_reduce(const float* __restrict__ psum,
                                                const float* __restrict__ psq,
                                                float* __restrict__ stats) {
  int w = threadIdx.x >> 6, lane = threadIdx.x & 63;
  const float* src = (w < 3) ? psum : psq;
  int c = (w < 3) ? w : (w - 3);
  float acc = 0.f;
  #pragma unroll
  for (int k = 0; k < 8; k++) acc += src[3 * (lane + 64 * k) + c];
  #pragma unroll
  for (int off = 32; off; off >>= 1) acc += __shfl_down(acc, off);
  if (lane == 0) stats[w] = acc;
}

// ---------------- Kg: gather live fc1 columns -> transposed Wgt[507][128][4] ----------------
__global__ __launch_bounds__(256) void k_gather(const float* __restrict__ fc1_w,
                                                float* __restrict__ Wgt) {
  int n = blockIdx.x;  // 128 rows
  for (int j = threadIdx.x; j < 2028; j += 256) {
    int c = j / 676;
    int rem = j - c * 676;
    int oy = rem / 26, ox = rem - oy * 26;
    int col = c * 4225 + ((5 * oy) >> 1) * 65 + ((5 * ox) >> 1);
    Wgt[(j >> 2) * 512 + n * 4 + (j & 3)] = fc1_w[n * 12675 + col];
  }
}

// ---------------- K2: fused BN + conv1 + relu + 1x1 conv2 + relu + fc1 + fc2 + log_softmax ----------------
__global__ __launch_bounds__(256) void k_fused(
    const float* __restrict__ x,       // [512,3,128,128]
    const float* __restrict__ stats,   // 6 floats
    const float* __restrict__ gamma, const float* __restrict__ beta,
    const float* __restrict__ w1, const float* __restrict__ b1,
    const float* __restrict__ w2, const float* __restrict__ b2,
    const float4* __restrict__ Wgt4,   // [507][128] float4
    const float* __restrict__ fc1_b,
    const float* __restrict__ fc2_w, const float* __restrict__ fc2_b,
    float* __restrict__ out)           // [512,10]
{
  __shared__ float s_w1[225];
  __shared__ float s_w2[3][3];
  __shared__ float s_scale[3], s_shift[3], s_b1[3], s_b2[3];
  __shared__ float s_feat[2028];
  __shared__ float s_red[256];
  __shared__ float s_f[128];
  __shared__ float s_logits[10];
  __shared__ float s_lse;

  const int tid = threadIdx.x;
  const int b = blockIdx.x;

  if (tid < 225) s_w1[tid] = w1[tid];
  if (tid < 9) s_w2[tid / 3][tid % 3] = w2[tid * 25];  // w2[o][c][0][0]
  if (tid < 3) {
    const float N = 512.f * 128.f * 128.f;
    float mean = stats[tid] / N;
    float var = stats[3 + tid] / N - mean * mean;
    float sc = gamma[tid] * rsqrtf(var + BN_EPS);
    s_scale[tid] = sc;
    s_shift[tid] = beta[tid] - mean * sc;
    s_b1[tid] = b1[tid];
    s_b2[tid] = b2[tid];
  }
  __syncthreads();

  // ---- conv1 (k5 s5 on pad-1 BN'd input) + relu + 1x1 conv2 + relu -> s_feat ----
  const float* xb = x + (size_t)b * 49152;
  for (int pos = tid; pos < 676; pos += 256) {
    int oy = pos / 26, ox = pos - oy * 26;
    int r0 = 5 * oy - 1, c0 = 5 * ox - 1;
    float a0 = s_b1[0], a1 = s_b1[1], a2 = s_b1[2];
    #pragma unroll
    for (int c = 0; c < 3; c++) {
      const float* xc = xb + c * 16384;
      float sc = s_scale[c], sh = s_shift[c];
      #pragma unroll
      for (int ky = 0; ky < 5; ky++) {
        int r = r0 + ky;
        if (r < 0 || r > 127) continue;
        const float* xr = xc + r * 128;
        const float* wk = s_w1 + c * 25 + ky * 5;
        #pragma unroll
        for (int kx = 0; kx < 5; kx++) {
          int cc = c0 + kx;
          if (cc < 0 || cc > 127) continue;
          float v = xr[cc] * sc + sh;
          a0 += wk[kx] * v;
          a1 += wk[75 + kx] * v;
          a2 += wk[150 + kx] * v;
        }
      }
    }
    float h0 = fmaxf(a0, 0.f), h1 = fmaxf(a1, 0.f), h2 = fmaxf(a2, 0.f);
    #pragma unroll
    for (int o = 0; o < 3; o++) {
      float h = s_b2[o] + s_w2[o][0] * h0 + s_w2[o][1] * h1 + s_w2[o][2] * h2;
      s_feat[o * 676 + pos] = fmaxf(h, 0.f);
    }
  }
  __syncthreads();

  // ---- fc1: 2 threads per neuron, coalesced transposed-weight stream ----
  {
    int n = tid & 127, h = tid >> 7;
    int v0 = h ? 253 : 0;
    int v1 = h ? 507 : 253;
    float acc = 0.f;
    for (int v = v0; v < v1; v++) {
      float4 w = Wgt4[v * 128 + n];
      int j = 4 * v;
      acc += w.x * s_feat[j] + w.y * s_feat[j + 1] + w.z * s_feat[j + 2] + w.w * s_feat[j + 3];
    }
    s_red[tid] = acc;
  }
  __syncthreads();
  if (tid < 128) {
    float f = fc1_b[tid] + s_red[tid] + s_red[tid + 128];
    s_f[tid] = fmaxf(f, 0.f);
  }
  __syncthreads();

  // ---- fc2 + log_softmax ----
  if (tid < 10) {
    float acc = fc2_b[tid];
    const float* wr = fc2_w + tid * 128;
    #pragma unroll 8
    for (int n = 0; n < 128; n++) acc += wr[n] * s_f[n];
    s_logits[tid] = acc;
  }
  __syncthreads();
  if (tid == 0) {
    float m = s_logits[0];
    #pragma unroll
    for (int k = 1; k < 10; k++) m = fmaxf(m, s_logits[k]);
    float se = 0.f;
    #pragma unroll
    for (int k = 0; k < 10; k++) se += expf(s_logits[k] - m);
    s_lse = m + logf(se);
  }
  __syncthreads();
  if (tid < 10) out[b * 10 + tid] = s_logits[tid] - s_lse;
}

extern "C" void kernel_launch(void* const* d_in, const int* in_sizes, int n_in,
                              void* d_out, int out_size, void* d_ws, size_t ws_size,
                              hipStream_t stream) {
  const float* x      = (const float*)d_in[0];
  const float* gamma  = (const float*)d_in[1];
  const float* beta   = (const float*)d_in[2];
  const float* w1     = (const float*)d_in[3];
  const float* b1     = (const float*)d_in[4];
  const float* w2     = (const float*)d_in[5];
  const float* b2     = (const float*)d_in[6];
  const float* fc1_w  = (const float*)d_in[7];
  const float* fc1_b  = (const float*)d_in[8];
  const float* fc2_w  = (const float*)d_in[9];
  const float* fc2_b  = (const float*)d_in[10];
  float* out = (float*)d_out;
  float* wsf = (float*)d_ws;

  float* stats = wsf;             // [0..5]
  float* psum  = wsf + 64;        // 1536
  float* psq   = wsf + 1664;      // 1536
  float* Wgt   = wsf + 4096;      // 507*512 floats = 1.04 MB

  k_stats<<<1536, 256, 0, stream>>>((const float4*)x, psum, psq);
  k_reduce<<<1, 384, 0, stream>>>(psum, psq, stats);
  k_gather<<<128, 256, 0, stream>>>(fc1_w, Wgt);
  k_fused<<<512, 256, 0, stream>>>(x, stats, gamma, beta, w1, b1, w2, b2,
                                   (const float4*)Wgt, fc1_b, fc2_w, fc2_b, out);
}

// Round 3
// 93.552 us; speedup vs baseline: 3.2378x; 2.3806x over previous
//
#include <hip/hip_runtime.h>

#define BN_EPS 1e-5f

// ws float layout:
//   [0..5]        stats
//   [64..1599]    psum[1536]
//   [1664..3199]  psq[1536]
//   [4096..]      Wgt  (507*512 floats = 1.04 MB)
//   [270336..]    feat (512*2028 floats = 4.15 MB)

// ---------------- K1: per-plane sum / sumsq over x [512,3,128,128] ----------------
__global__ __launch_bounds__(256) void k_stats(const float4* __restrict__ x4,
                                               float* __restrict__ psum,
                                               float* __restrict__ psq) {
  const int p = blockIdx.x;  // plane id: b*3 + c
  const float4* base = x4 + (size_t)p * 4096;
  float s = 0.f, q = 0.f;
  #pragma unroll
  for (int i = 0; i < 16; i++) {
    float4 a = base[i * 256 + threadIdx.x];
    s += (a.x + a.y) + (a.z + a.w);
    q += (a.x * a.x + a.y * a.y) + (a.z * a.z + a.w * a.w);
  }
  #pragma unroll
  for (int off = 32; off; off >>= 1) {
    s += __shfl_down(s, off);
    q += __shfl_down(q, off);
  }
  __shared__ float rs[4], rq[4];
  int lane = threadIdx.x & 63, w = threadIdx.x >> 6;
  if (lane == 0) { rs[w] = s; rq[w] = q; }
  __syncthreads();
  if (threadIdx.x == 0) {
    psum[p] = (rs[0] + rs[1]) + (rs[2] + rs[3]);
    psq[p]  = (rq[0] + rq[1]) + (rq[2] + rq[3]);
  }
}

// ---------------- K1b: fold 1536 partials -> 6 stats ----------------
__global__ __launch_bounds__(384) void k_reduce(const float* __restrict__ psum,
                                                const float* __restrict__ psq,
                                                float* __restrict__ stats) {
  int w = threadIdx.x >> 6, lane = threadIdx.x & 63;
  const float* src = (w < 3) ? psum : psq;
  int c = (w < 3) ? w : (w - 3);
  float acc = 0.f;
  #pragma unroll
  for (int k = 0; k < 8; k++) acc += src[3 * (lane + 64 * k) + c];
  #pragma unroll
  for (int off = 32; off; off >>= 1) acc += __shfl_down(acc, off);
  if (lane == 0) stats[w] = acc;
}

// ---------------- Kg: gather live fc1 columns -> transposed Wgt[507][128][4] ----------------
__global__ __launch_bounds__(256) void k_gather(const float* __restrict__ fc1_w,
                                                float* __restrict__ Wgt) {
  int n = blockIdx.x;  // 128 rows
  for (int j = threadIdx.x; j < 2028; j += 256) {
    int c = j / 676;
    int rem = j - c * 676;
    int oy = rem / 26, ox = rem - oy * 26;
    int col = c * 4225 + ((5 * oy) >> 1) * 65 + ((5 * ox) >> 1);
    Wgt[(j >> 2) * 512 + n * 4 + (j & 3)] = fc1_w[n * 12675 + col];
  }
}

// ---------------- K2: BN + conv1(k5,s5,pad1) + relu + 1x1 conv2 + relu -> feat ----------------
// One thread per (b, pos): 512*676 = 346112 threads, 1352 blocks.
__global__ __launch_bounds__(256) void k_conv(
    const float* __restrict__ x,       // [512,3,128,128]
    const float* __restrict__ stats,
    const float* __restrict__ gamma, const float* __restrict__ beta,
    const float* __restrict__ w1, const float* __restrict__ b1,
    const float* __restrict__ w2, const float* __restrict__ b2,
    float* __restrict__ feat)          // [512][3*676]
{
  __shared__ float s_w1[225];
  __shared__ float s_w2[9];
  __shared__ float s_scale[3], s_shift[3], s_b1[3], s_b2[3];
  const int tid = threadIdx.x;
  if (tid < 225) s_w1[tid] = w1[tid];
  if (tid < 9) s_w2[tid] = w2[tid * 25];  // w2[o][c][0][0]
  if (tid < 3) {
    const float N = 512.f * 128.f * 128.f;
    float mean = stats[tid] / N;
    float var = stats[3 + tid] / N - mean * mean;
    float sc = gamma[tid] * rsqrtf(var + BN_EPS);
    s_scale[tid] = sc;
    s_shift[tid] = beta[tid] - mean * sc;
    s_b1[tid] = b1[tid];
    s_b2[tid] = b2[tid];
  }
  __syncthreads();

  int gpos = blockIdx.x * 256 + tid;
  int b = gpos / 676;
  int pos = gpos - b * 676;
  int oy = pos / 26, ox = pos - oy * 26;
  int r0 = 5 * oy - 1, c0 = 5 * ox - 1;

  const float* xb = x + (size_t)b * 49152;
  float a0 = s_b1[0], a1 = s_b1[1], a2 = s_b1[2];
  #pragma unroll
  for (int c = 0; c < 3; c++) {
    const float* xc = xb + c * 16384;
    float sc = s_scale[c], sh = s_shift[c];
    #pragma unroll
    for (int ky = 0; ky < 5; ky++) {
      int r = r0 + ky;
      if (r < 0 || r > 127) continue;
      const float* xr = xc + r * 128;
      const float* wk = s_w1 + c * 25 + ky * 5;
      #pragma unroll
      for (int kx = 0; kx < 5; kx++) {
        int cc = c0 + kx;
        if (cc < 0 || cc > 127) continue;
        float v = xr[cc] * sc + sh;
        a0 += wk[kx] * v;
        a1 += wk[75 + kx] * v;
        a2 += wk[150 + kx] * v;
      }
    }
  }
  float h0 = fmaxf(a0, 0.f), h1 = fmaxf(a1, 0.f), h2 = fmaxf(a2, 0.f);
  float* fb = feat + (size_t)b * 2028;
  #pragma unroll
  for (int o = 0; o < 3; o++) {
    float h = s_b2[o] + s_w2[3 * o] * h0 + s_w2[3 * o + 1] * h1 + s_w2[3 * o + 2] * h2;
    fb[o * 676 + pos] = fmaxf(h, 0.f);
  }
}

// ---------------- K3: fc1 + relu + fc2 + log_softmax, one block (512 thr) per sample ----------------
__global__ __launch_bounds__(512) void k_fc(
    const float4* __restrict__ feat4,  // [512][507]
    const float4* __restrict__ Wgt4,   // [507][128]
    const float* __restrict__ fc1_b,
    const float* __restrict__ fc2_w, const float* __restrict__ fc2_b,
    float* __restrict__ out)           // [512,10]
{
  __shared__ float4 s_feat4[507];
  __shared__ float s_red[512];
  __shared__ float s_f[128];
  __shared__ float s_logits[10];
  __shared__ float s_lse;

  const int tid = threadIdx.x;
  const int b = blockIdx.x;

  if (tid < 507) s_feat4[tid] = feat4[(size_t)b * 507 + tid];
  __syncthreads();

  // fc1: 4 threads per neuron; within a wave all lanes share h -> LDS broadcast
  {
    int n = tid & 127, h = tid >> 7;
    int v0 = h * 127;
    int v1 = (h == 3) ? 507 : v0 + 127;
    float acc = 0.f;
    for (int v = v0; v < v1; v++) {
      float4 w = Wgt4[v * 128 + n];
      float4 f = s_feat4[v];
      acc += w.x * f.x + w.y * f.y + w.z * f.z + w.w * f.w;
    }
    s_red[tid] = acc;
  }
  __syncthreads();
  if (tid < 128) {
    float f = fc1_b[tid] + (s_red[tid] + s_red[tid + 128]) + (s_red[tid + 256] + s_red[tid + 384]);
    s_f[tid] = fmaxf(f, 0.f);
  }
  __syncthreads();

  if (tid < 10) {
    float acc = fc2_b[tid];
    const float* wr = fc2_w + tid * 128;
    #pragma unroll 8
    for (int n = 0; n < 128; n++) acc += wr[n] * s_f[n];
    s_logits[tid] = acc;
  }
  __syncthreads();
  if (tid == 0) {
    float m = s_logits[0];
    #pragma unroll
    for (int k = 1; k < 10; k++) m = fmaxf(m, s_logits[k]);
    float se = 0.f;
    #pragma unroll
    for (int k = 0; k < 10; k++) se += expf(s_logits[k] - m);
    s_lse = m + logf(se);
  }
  __syncthreads();
  if (tid < 10) out[b * 10 + tid] = s_logits[tid] - s_lse;
}

extern "C" void kernel_launch(void* const* d_in, const int* in_sizes, int n_in,
                              void* d_out, int out_size, void* d_ws, size_t ws_size,
                              hipStream_t stream) {
  const float* x      = (const float*)d_in[0];
  const float* gamma  = (const float*)d_in[1];
  const float* beta   = (const float*)d_in[2];
  const float* w1     = (const float*)d_in[3];
  const float* b1     = (const float*)d_in[4];
  const float* w2     = (const float*)d_in[5];
  const float* b2     = (const float*)d_in[6];
  const float* fc1_w  = (const float*)d_in[7];
  const float* fc1_b  = (const float*)d_in[8];
  const float* fc2_w  = (const float*)d_in[9];
  const float* fc2_b  = (const float*)d_in[10];
  float* out = (float*)d_out;
  float* wsf = (float*)d_ws;

  float* stats = wsf;             // [0..5]
  float* psum  = wsf + 64;        // 1536
  float* psq   = wsf + 1664;      // 1536
  float* Wgt   = wsf + 4096;      // 507*512 floats
  float* feat  = wsf + 270336;    // 512*2028 floats

  k_stats<<<1536, 256, 0, stream>>>((const float4*)x, psum, psq);
  k_reduce<<<1, 384, 0, stream>>>(psum, psq, stats);
  k_gather<<<128, 256, 0, stream>>>(fc1_w, Wgt);
  k_conv<<<1352, 256, 0, stream>>>(x, stats, gamma, beta, w1, b1, w2, b2, feat);
  k_fc<<<512, 512, 0, stream>>>((const float4*)feat, (const float4*)Wgt,
                                fc1_b, fc2_w, fc2_b, out);
}

// Round 4
// 74.439 us; speedup vs baseline: 4.0692x; 1.2568x over previous
//
#include <hip/hip_runtime.h>

#define BN_EPS 1e-5f

typedef short short8 __attribute__((ext_vector_type(8)));
typedef float f32x4 __attribute__((ext_vector_type(4)));
typedef unsigned short ushort;

__device__ inline ushort f2bf(float f) {
  unsigned int u = __float_as_uint(f);
  u += 0x7FFFu + ((u >> 16) & 1u);
  return (ushort)(u >> 16);
}

// ws float-word layout:
//   [0..5]        stats
//   [64..1599]    psum[1536]
//   [1664..3199]  psq[1536]
//   [4096..]      WgtB  bf16 [8][64][64][8]  (512 KB = 131072 words)
//   [139264..]    featB bf16 [512][2048]     (2 MB = 524288 words)

// ---------------- K1: per-plane sum / sumsq over x [512,3,128,128] ----------------
__global__ __launch_bounds__(256) void k_stats(const float4* __restrict__ x4,
                                               float* __restrict__ psum,
                                               float* __restrict__ psq) {
  const int p = blockIdx.x;  // plane id: b*3 + c
  const float4* base = x4 + (size_t)p * 4096;
  float s = 0.f, q = 0.f;
  #pragma unroll
  for (int i = 0; i < 16; i++) {
    float4 a = base[i * 256 + threadIdx.x];
    s += (a.x + a.y) + (a.z + a.w);
    q += (a.x * a.x + a.y * a.y) + (a.z * a.z + a.w * a.w);
  }
  #pragma unroll
  for (int off = 32; off; off >>= 1) {
    s += __shfl_down(s, off);
    q += __shfl_down(q, off);
  }
  __shared__ float rs[4], rq[4];
  int lane = threadIdx.x & 63, w = threadIdx.x >> 6;
  if (lane == 0) { rs[w] = s; rq[w] = q; }
  __syncthreads();
  if (threadIdx.x == 0) {
    psum[p] = (rs[0] + rs[1]) + (rs[2] + rs[3]);
    psq[p]  = (rq[0] + rq[1]) + (rq[2] + rq[3]);
  }
}

// ---------------- K1b: fold 1536 partials -> 6 stats ----------------
__global__ __launch_bounds__(384) void k_reduce(const float* __restrict__ psum,
                                                const float* __restrict__ psq,
                                                float* __restrict__ stats) {
  int w = threadIdx.x >> 6, lane = threadIdx.x & 63;
  const float* src = (w < 3) ? psum : psq;
  int c = (w < 3) ? w : (w - 3);
  float acc = 0.f;
  #pragma unroll
  for (int k = 0; k < 8; k++) acc += src[3 * (lane + 64 * k) + c];
  #pragma unroll
  for (int off = 32; off; off >>= 1) acc += __shfl_down(acc, off);
  if (lane == 0) stats[w] = acc;
}

// ---------------- Kg: gather live fc1 columns -> bf16 B-fragment layout ----------------
// WgtB[((t*64 + kk)*64 + l)*8 + j] = B element (k = kk*32 + (l>>4)*8 + j, n = t*16 + (l&15))
__device__ inline float gval(const float* __restrict__ row, int k) {
  if (k >= 2028) return 0.f;
  int c = k / 676;
  int rem = k - c * 676;
  int oy = rem / 26, ox = rem - oy * 26;
  int col = c * 4225 + ((5 * oy) >> 1) * 65 + ((5 * ox) >> 1);
  return row[col];
}

__global__ __launch_bounds__(256) void k_gather(const float* __restrict__ fc1_w,
                                                ushort* __restrict__ WgtB) {
  int gid = blockIdx.x * 256 + threadIdx.x;  // 32768 total
  int l = gid & 63;
  int n = ((gid >> 12) << 4) + (l & 15);     // t*16 + (l&15)
  int kbase = (((gid >> 6) & 63) << 5) + ((l >> 4) << 3);
  const float* row = fc1_w + n * 12675;
  uint4 o;
  unsigned int w[4];
  #pragma unroll
  for (int i = 0; i < 4; i++) {
    ushort lo = f2bf(gval(row, kbase + 2 * i));
    ushort hi = f2bf(gval(row, kbase + 2 * i + 1));
    w[i] = (unsigned int)lo | ((unsigned int)hi << 16);
  }
  o.x = w[0]; o.y = w[1]; o.z = w[2]; o.w = w[3];
  ((uint4*)WgtB)[gid] = o;
}

// ---------------- K2: BN + conv1(k5,s5,pad1) + relu + 1x1 conv2 + relu -> bf16 feat ----------------
__global__ __launch_bounds__(256) void k_conv(
    const float* __restrict__ x,       // [512,3,128,128]
    const float* __restrict__ stats,
    const float* __restrict__ gamma, const float* __restrict__ beta,
    const float* __restrict__ w1, const float* __restrict__ b1,
    const float* __restrict__ w2, const float* __restrict__ b2,
    ushort* __restrict__ featB)        // [512][2048] bf16
{
  __shared__ float s_w1[225];
  __shared__ float s_w2[9];
  __shared__ float s_scale[3], s_shift[3], s_b1[3], s_b2[3];
  const int tid = threadIdx.x;
  if (tid < 225) s_w1[tid] = w1[tid];
  if (tid < 9) s_w2[tid] = w2[tid * 25];  // w2[o][c][0][0]
  if (tid < 3) {
    const float N = 512.f * 128.f * 128.f;
    float mean = stats[tid] / N;
    float var = stats[3 + tid] / N - mean * mean;
    float sc = gamma[tid] * rsqrtf(var + BN_EPS);
    s_scale[tid] = sc;
    s_shift[tid] = beta[tid] - mean * sc;
    s_b1[tid] = b1[tid];
    s_b2[tid] = b2[tid];
  }
  __syncthreads();

  int gpos = blockIdx.x * 256 + tid;
  int b = gpos / 676;
  int pos = gpos - b * 676;
  int oy = pos / 26, ox = pos - oy * 26;
  int r0 = 5 * oy - 1, c0 = 5 * ox - 1;

  const float* xb = x + (size_t)b * 49152;
  float a0 = s_b1[0], a1 = s_b1[1], a2 = s_b1[2];
  #pragma unroll
  for (int c = 0; c < 3; c++) {
    const float* xc = xb + c * 16384;
    float sc = s_scale[c], sh = s_shift[c];
    #pragma unroll
    for (int ky = 0; ky < 5; ky++) {
      int r = r0 + ky;
      if (r < 0 || r > 127) continue;
      const float* xr = xc + r * 128;
      const float* wk = s_w1 + c * 25 + ky * 5;
      #pragma unroll
      for (int kx = 0; kx < 5; kx++) {
        int cc = c0 + kx;
        if (cc < 0 || cc > 127) continue;
        float v = xr[cc] * sc + sh;
        a0 += wk[kx] * v;
        a1 += wk[75 + kx] * v;
        a2 += wk[150 + kx] * v;
      }
    }
  }
  float h0 = fmaxf(a0, 0.f), h1 = fmaxf(a1, 0.f), h2 = fmaxf(a2, 0.f);
  ushort* fb = featB + (size_t)b * 2048;
  #pragma unroll
  for (int o = 0; o < 3; o++) {
    float h = s_b2[o] + s_w2[3 * o] * h0 + s_w2[3 * o + 1] * h1 + s_w2[3 * o + 2] * h2;
    fb[o * 676 + pos] = f2bf(fmaxf(h, 0.f));
  }
  if (pos < 20) fb[2028 + pos] = 0;  // zero K-pad
}

// ---------------- K3: fc1 via MFMA + relu + fc2 + log_softmax ----------------
// 32 blocks (16 samples each) x 512 threads; wave w = N-tile w (16 neurons).
__global__ __launch_bounds__(512) void k_fc(
    const ushort* __restrict__ featB,  // [512][2048] bf16
    const ushort* __restrict__ WgtB,   // B-fragment layout
    const float* __restrict__ fc1_b,
    const float* __restrict__ fc2_w, const float* __restrict__ fc2_b,
    float* __restrict__ out)           // [512,10]
{
  __shared__ float s_f[16][132];
  __shared__ float s_lg[16][10];
  const int tid = threadIdx.x;
  const int lane = tid & 63;
  const int t = tid >> 6;           // N-tile 0..7
  const int m0 = blockIdx.x * 16;

  const ushort* aptr = featB + (size_t)(m0 + (lane & 15)) * 2048 + ((lane >> 4) << 3);
  const ushort* bptr = WgtB + ((size_t)t * 4096 + lane) * 8;

  f32x4 acc = {0.f, 0.f, 0.f, 0.f};
  #pragma unroll 4
  for (int kk = 0; kk < 64; kk++) {
    short8 a = *(const short8*)(aptr + kk * 32);
    short8 bfr = *(const short8*)(bptr + kk * 512);
    acc = __builtin_amdgcn_mfma_f32_16x16x32_bf16(a, bfr, acc, 0, 0, 0);
  }
  {
    int n = t * 16 + (lane & 15);       // D: col = lane&15 (+tile), row = (lane>>4)*4 + r
    float bias = fc1_b[n];
    int mb = (lane >> 4) << 2;
    #pragma unroll
    for (int r = 0; r < 4; r++)
      s_f[mb + r][n] = fmaxf(acc[r] + bias, 0.f);
  }
  __syncthreads();

  if (tid < 160) {
    int m = tid & 15, q = tid >> 4;
    const float* wr = fc2_w + q * 128;
    float a2 = fc2_b[q];
    #pragma unroll 8
    for (int k = 0; k < 128; k++) a2 += wr[k] * s_f[m][k];
    s_lg[m][q] = a2;
  }
  __syncthreads();

  if (tid < 16) {
    float mx = s_lg[tid][0];
    #pragma unroll
    for (int q = 1; q < 10; q++) mx = fmaxf(mx, s_lg[tid][q]);
    float se = 0.f;
    #pragma unroll
    for (int q = 0; q < 10; q++) se += expf(s_lg[tid][q] - mx);
    float lse = mx + logf(se);
    float* op = out + (size_t)(m0 + tid) * 10;
    #pragma unroll
    for (int q = 0; q < 10; q++) op[q] = s_lg[tid][q] - lse;
  }
}

extern "C" void kernel_launch(void* const* d_in, const int* in_sizes, int n_in,
                              void* d_out, int out_size, void* d_ws, size_t ws_size,
                              hipStream_t stream) {
  const float* x      = (const float*)d_in[0];
  const float* gamma  = (const float*)d_in[1];
  const float* beta   = (const float*)d_in[2];
  const float* w1     = (const float*)d_in[3];
  const float* b1     = (const float*)d_in[4];
  const float* w2     = (const float*)d_in[5];
  const float* b2     = (const float*)d_in[6];
  const float* fc1_w  = (const float*)d_in[7];
  const float* fc1_b  = (const float*)d_in[8];
  const float* fc2_w  = (const float*)d_in[9];
  const float* fc2_b  = (const float*)d_in[10];
  float* out = (float*)d_out;
  float* wsf = (float*)d_ws;

  float* stats  = wsf;              // [0..5]
  float* psum   = wsf + 64;         // 1536
  float* psq    = wsf + 1664;       // 1536
  ushort* WgtB  = (ushort*)(wsf + 4096);    // 512 KB bf16
  ushort* featB = (ushort*)(wsf + 139264);  // 2 MB bf16

  k_stats<<<1536, 256, 0, stream>>>((const float4*)x, psum, psq);
  k_reduce<<<1, 384, 0, stream>>>(psum, psq, stats);
  k_gather<<<128, 256, 0, stream>>>(fc1_w, WgtB);
  k_conv<<<1352, 256, 0, stream>>>(x, stats, gamma, beta, w1, b1, w2, b2, featB);
  k_fc<<<32, 512, 0, stream>>>(featB, WgtB, fc1_b, fc2_w, fc2_b, out);
}

// Round 5
// 73.351 us; speedup vs baseline: 4.1295x; 1.0148x over previous
//
#include <hip/hip_runtime.h>

#define BN_EPS 1e-5f

typedef short short8 __attribute__((ext_vector_type(8)));
typedef float f32x4 __attribute__((ext_vector_type(4)));
typedef unsigned short ushort;

__device__ inline ushort f2bf(float f) {
  unsigned int u = __float_as_uint(f);
  u += 0x7FFFu + ((u >> 16) & 1u);
  return (ushort)(u >> 16);
}

// ws float-word layout:
//   [0..5]         stats (3 sums, 3 sumsqs)
//   [64..8223]     psumS [6][1360]  (per-K1-block partials)
//   [16384..]      WgtB  bf16 [8][64][64][8]   (512 KB = 131072 words)
//   [262144..]     featB bf16 [512][2048]      (2 MB  = 524288 words)
//   [786432..]     S     [9][346112] fp32 raw conv partials (12.5 MB)

#define NPOS 346112  // 512*676

// ---------------- K1: single x pass -> raw conv partials S[c*3+o] + stats partials ----
__global__ __launch_bounds__(256) void k_convraw(
    const float* __restrict__ x,       // [512,3,128,128]
    const float* __restrict__ w1,      // [3,3,5,5]
    float* __restrict__ S,             // [9][NPOS]
    float* __restrict__ psumS)         // [6][1360]
{
  __shared__ float s_w1[225];
  const int tid = threadIdx.x;
  if (tid < 225) s_w1[tid] = w1[tid];
  __syncthreads();

  int gpos = blockIdx.x * 256 + tid;   // exactly NPOS threads
  int b = gpos / 676;
  int pos = gpos - b * 676;
  int oy = pos / 26, ox = pos - oy * 26;
  int r0 = 5 * oy - 1, c0 = 5 * ox - 1;

  const float* xb = x + (size_t)b * 49152;
  float a00 = 0.f, a01 = 0.f, a02 = 0.f;   // [c][o]
  float a10 = 0.f, a11 = 0.f, a12 = 0.f;
  float a20 = 0.f, a21 = 0.f, a22 = 0.f;
  float s0 = 0.f, s1 = 0.f, s2 = 0.f, q0 = 0.f, q1 = 0.f, q2 = 0.f;

  #pragma unroll
  for (int c = 0; c < 3; c++) {
    const float* xc = xb + c * 16384;
    #pragma unroll
    for (int ky = 0; ky < 5; ky++) {
      int r = r0 + ky;
      if (r < 0 || r > 127) continue;
      const float* xr = xc + r * 128;
      const float* wk = s_w1 + c * 25 + ky * 5;
      #pragma unroll
      for (int kx = 0; kx < 5; kx++) {
        int cc = c0 + kx;
        if (cc < 0 || cc > 127) continue;
        float v = xr[cc];
        float w0 = wk[kx], w1v = wk[75 + kx], w2v = wk[150 + kx];
        if (c == 0)      { s0 += v; q0 += v * v; a00 += w0 * v; a01 += w1v * v; a02 += w2v * v; }
        else if (c == 1) { s1 += v; q1 += v * v; a10 += w0 * v; a11 += w1v * v; a12 += w2v * v; }
        else             { s2 += v; q2 += v * v; a20 += w0 * v; a21 += w1v * v; a22 += w2v * v; }
      }
    }
  }

  S[(size_t)0 * NPOS + gpos] = a00;
  S[(size_t)1 * NPOS + gpos] = a01;
  S[(size_t)2 * NPOS + gpos] = a02;
  S[(size_t)3 * NPOS + gpos] = a10;
  S[(size_t)4 * NPOS + gpos] = a11;
  S[(size_t)5 * NPOS + gpos] = a12;
  S[(size_t)6 * NPOS + gpos] = a20;
  S[(size_t)7 * NPOS + gpos] = a21;
  S[(size_t)8 * NPOS + gpos] = a22;

  #pragma unroll
  for (int off = 32; off; off >>= 1) {
    s0 += __shfl_down(s0, off); q0 += __shfl_down(q0, off);
    s1 += __shfl_down(s1, off); q1 += __shfl_down(q1, off);
    s2 += __shfl_down(s2, off); q2 += __shfl_down(q2, off);
  }
  __shared__ float red[4][6];
  int lane = tid & 63, wv = tid >> 6;
  if (lane == 0) {
    red[wv][0] = s0; red[wv][1] = s1; red[wv][2] = s2;
    red[wv][3] = q0; red[wv][4] = q1; red[wv][5] = q2;
  }
  __syncthreads();
  if (tid < 6)
    psumS[tid * 1360 + blockIdx.x] =
        (red[0][tid] + red[1][tid]) + (red[2][tid] + red[3][tid]);
}

// ---------------- K1b: fold 1352 partials -> 6 stats ----------------
__global__ __launch_bounds__(384) void k_reduce(const float* __restrict__ psumS,
                                                float* __restrict__ stats) {
  int w = threadIdx.x >> 6, lane = threadIdx.x & 63;
  const float* src = psumS + w * 1360;
  float acc = 0.f;
  for (int k = lane; k < 1352; k += 64) acc += src[k];
  #pragma unroll
  for (int off = 32; off; off >>= 1) acc += __shfl_down(acc, off);
  if (lane == 0) stats[w] = acc;
}

// ---------------- Kg: gather live fc1 columns -> bf16 B-fragment layout ----------------
__device__ inline float gval(const float* __restrict__ row, int k) {
  if (k >= 2028) return 0.f;
  int c = k / 676;
  int rem = k - c * 676;
  int oy = rem / 26, ox = rem - oy * 26;
  int col = c * 4225 + ((5 * oy) >> 1) * 65 + ((5 * ox) >> 1);
  return row[col];
}

__global__ __launch_bounds__(256) void k_gather(const float* __restrict__ fc1_w,
                                                ushort* __restrict__ WgtB) {
  int gid = blockIdx.x * 256 + threadIdx.x;  // 32768 total
  int l = gid & 63;
  int n = ((gid >> 12) << 4) + (l & 15);
  int kbase = (((gid >> 6) & 63) << 5) + ((l >> 4) << 3);
  const float* row = fc1_w + n * 12675;
  uint4 o;
  unsigned int w[4];
  #pragma unroll
  for (int i = 0; i < 4; i++) {
    ushort lo = f2bf(gval(row, kbase + 2 * i));
    ushort hi = f2bf(gval(row, kbase + 2 * i + 1));
    w[i] = (unsigned int)lo | ((unsigned int)hi << 16);
  }
  o.x = w[0]; o.y = w[1]; o.z = w[2]; o.w = w[3];
  ((uint4*)WgtB)[gid] = o;
}

// ---------------- K2: combine S + stats -> BN'd conv1 + relu + 1x1 conv2 + relu -> bf16 feat ----
__global__ __launch_bounds__(256) void k_combine(
    const float* __restrict__ S,       // [9][NPOS]
    const float* __restrict__ stats,
    const float* __restrict__ gamma, const float* __restrict__ beta,
    const float* __restrict__ w1, const float* __restrict__ b1,
    const float* __restrict__ w2, const float* __restrict__ b2,
    ushort* __restrict__ featB)        // [512][2048] bf16
{
  __shared__ float s_w1[225];
  __shared__ float s_w2[9];
  __shared__ float s_scale[3], s_shift[3], s_b1[3], s_b2[3];
  __shared__ float s_T[9][9];          // [rcl*3+ccl][o*3+c]
  const int tid = threadIdx.x;
  if (tid < 225) s_w1[tid] = w1[tid];
  if (tid < 9) s_w2[tid] = w2[tid * 25];
  if (tid < 3) {
    const float N = 512.f * 128.f * 128.f;
    float mean = stats[tid] / N;
    float var = stats[3 + tid] / N - mean * mean;
    float sc = gamma[tid] * rsqrtf(var + BN_EPS);
    s_scale[tid] = sc;
    s_shift[tid] = beta[tid] - mean * sc;
    s_b1[tid] = b1[tid];
    s_b2[tid] = b2[tid];
  }
  __syncthreads();
  if (tid < 81) {
    int cls = tid / 9, oc = tid - (tid / 9) * 9;
    int rcl = cls / 3, ccl = cls - rcl * 3;
    int o = oc / 3, c = oc - o * 3;
    int ky0 = (rcl == 0) ? 1 : 0, ky1 = (rcl == 2) ? 3 : 4;
    int kx0 = (ccl == 0) ? 1 : 0, kx1 = (ccl == 2) ? 3 : 4;
    float t = 0.f;
    for (int ky = ky0; ky <= ky1; ky++)
      for (int kx = kx0; kx <= kx1; kx++)
        t += s_w1[o * 75 + c * 25 + ky * 5 + kx];
    s_T[cls][oc] = t;
  }
  __syncthreads();

  int gpos = blockIdx.x * 256 + tid;
  int b = gpos / 676;
  int pos = gpos - b * 676;
  int oy = pos / 26, ox = pos - oy * 26;
  int rcl = (oy == 0) ? 0 : ((oy == 25) ? 2 : 1);
  int ccl = (ox == 0) ? 0 : ((ox == 25) ? 2 : 1);
  int cls = rcl * 3 + ccl;

  float h[3];
  #pragma unroll
  for (int o = 0; o < 3; o++) {
    float a = s_b1[o];
    #pragma unroll
    for (int c = 0; c < 3; c++) {
      a += s_scale[c] * S[(size_t)(c * 3 + o) * NPOS + gpos];
      a += s_shift[c] * s_T[cls][o * 3 + c];
    }
    h[o] = fmaxf(a, 0.f);
  }
  ushort* fb = featB + (size_t)b * 2048;
  #pragma unroll
  for (int o = 0; o < 3; o++) {
    float v = s_b2[o] + s_w2[3 * o] * h[0] + s_w2[3 * o + 1] * h[1] + s_w2[3 * o + 2] * h[2];
    fb[o * 676 + pos] = f2bf(fmaxf(v, 0.f));
  }
  if (pos < 20) fb[2028 + pos] = 0;  // zero K-pad
}

// ---------------- K3: fc1 via MFMA + relu + fc2 + log_softmax ----------------
__global__ __launch_bounds__(512) void k_fc(
    const ushort* __restrict__ featB,  // [512][2048] bf16
    const ushort* __restrict__ WgtB,   // B-fragment layout
    const float* __restrict__ fc1_b,
    const float* __restrict__ fc2_w, const float* __restrict__ fc2_b,
    float* __restrict__ out)           // [512,10]
{
  __shared__ float s_f[16][132];
  __shared__ float s_lg[16][10];
  const int tid = threadIdx.x;
  const int lane = tid & 63;
  const int t = tid >> 6;           // N-tile 0..7
  const int m0 = blockIdx.x * 16;

  const ushort* aptr = featB + (size_t)(m0 + (lane & 15)) * 2048 + ((lane >> 4) << 3);
  const ushort* bptr = WgtB + ((size_t)t * 4096 + lane) * 8;

  f32x4 acc = {0.f, 0.f, 0.f, 0.f};
  #pragma unroll 4
  for (int kk = 0; kk < 64; kk++) {
    short8 a = *(const short8*)(aptr + kk * 32);
    short8 bfr = *(const short8*)(bptr + kk * 512);
    acc = __builtin_amdgcn_mfma_f32_16x16x32_bf16(a, bfr, acc, 0, 0, 0);
  }
  {
    int n = t * 16 + (lane & 15);
    float bias = fc1_b[n];
    int mb = (lane >> 4) << 2;
    #pragma unroll
    for (int r = 0; r < 4; r++)
      s_f[mb + r][n] = fmaxf(acc[r] + bias, 0.f);
  }
  __syncthreads();

  if (tid < 160) {
    int m = tid & 15, q = tid >> 4;
    const float* wr = fc2_w + q * 128;
    float a2 = fc2_b[q];
    #pragma unroll 8
    for (int k = 0; k < 128; k++) a2 += wr[k] * s_f[m][k];
    s_lg[m][q] = a2;
  }
  __syncthreads();

  if (tid < 16) {
    float mx = s_lg[tid][0];
    #pragma unroll
    for (int q = 1; q < 10; q++) mx = fmaxf(mx, s_lg[tid][q]);
    float se = 0.f;
    #pragma unroll
    for (int q = 0; q < 10; q++) se += expf(s_lg[tid][q] - mx);
    float lse = mx + logf(se);
    float* op = out + (size_t)(m0 + tid) * 10;
    #pragma unroll
    for (int q = 0; q < 10; q++) op[q] = s_lg[tid][q] - lse;
  }
}

extern "C" void kernel_launch(void* const* d_in, const int* in_sizes, int n_in,
                              void* d_out, int out_size, void* d_ws, size_t ws_size,
                              hipStream_t stream) {
  const float* x      = (const float*)d_in[0];
  const float* gamma  = (const float*)d_in[1];
  const float* beta   = (const float*)d_in[2];
  const float* w1     = (const float*)d_in[3];
  const float* b1     = (const float*)d_in[4];
  const float* w2     = (const float*)d_in[5];
  const float* b2     = (const float*)d_in[6];
  const float* fc1_w  = (const float*)d_in[7];
  const float* fc1_b  = (const float*)d_in[8];
  const float* fc2_w  = (const float*)d_in[9];
  const float* fc2_b  = (const float*)d_in[10];
  float* out = (float*)d_out;
  float* wsf = (float*)d_ws;

  float* stats  = wsf;                      // [0..5]
  float* psumS  = wsf + 64;                 // [6][1360]
  ushort* WgtB  = (ushort*)(wsf + 16384);   // 512 KB bf16
  ushort* featB = (ushort*)(wsf + 262144);  // 2 MB bf16
  float* S      = wsf + 786432;             // [9][NPOS] = 12.5 MB

  k_convraw<<<1352, 256, 0, stream>>>(x, w1, S, psumS);
  k_gather<<<128, 256, 0, stream>>>(fc1_w, WgtB);
  k_reduce<<<1, 384, 0, stream>>>(psumS, stats);
  k_combine<<<1352, 256, 0, stream>>>(S, stats, gamma, beta, w1, b1, w2, b2, featB);
  k_fc<<<32, 512, 0, stream>>>(featB, WgtB, fc1_b, fc2_w, fc2_b, out);
}

// Round 6
// 60.072 us; speedup vs baseline: 5.0423x; 1.2210x over previous
//
#include <hip/hip_runtime.h>

#define BN_EPS 1e-5f

typedef short short8 __attribute__((ext_vector_type(8)));
typedef float f32x4 __attribute__((ext_vector_type(4)));
typedef unsigned short ushort;

__device__ inline ushort f2bf(float f) {
  unsigned int u = __float_as_uint(f);
  u += 0x7FFFu + ((u >> 16) & 1u);
  return (ushort)(u >> 16);
}

// ws float-word layout:
//   [0..5]         stats (3 sums, 3 sumsqs)
//   [64..3135]     psumS [6][512]  (per-sample-plane partials)
//   [16384..]      WgtB  bf16 [8][64][64][8]   (512 KB = 131072 words)
//   [262144..]     featB bf16 [512][2048]      (2 MB  = 524288 words)
//   [786432..]     S     [9][346112] fp32 raw conv partials (12.5 MB)

#define NPOS 346112  // 512*676
#define LROW 144     // padded LDS row stride (16B-aligned rows: 144*4 % 16 == 0)

// ---------------- K1: LDS-staged single x pass -> raw conv partials S + stats ----------------
// One block per sample b. Channel-looped: stage plane into zero-padded LDS tile,
// compute 25-tap partials for all 676 positions with immediate-offset ds_reads.
__global__ __launch_bounds__(256) void k_convraw(
    const float* __restrict__ x,       // [512,3,128,128]
    const float* __restrict__ w1g,     // [3,3,5,5] read via uniform (SGPR) loads
    float* __restrict__ S,             // [9][NPOS]
    float* __restrict__ psumS)         // [6][512]
{
  __shared__ float s_xp[130 * LROW];   // rows -1..128 -> 0..129 ; cols -1..128 -> 3..132
  __shared__ float red[4][6];
  const int tid = threadIdx.x;
  const int b = blockIdx.x;

  // zero the pad borders once (rows 0 & 129 full; cols 3 & 132 for rows 1..128)
  for (int i = tid; i < 2 * LROW; i += 256) {
    int r = (i < LROW) ? 0 : 129;
    int c = (i < LROW) ? i : i - LROW;
    s_xp[r * LROW + c] = 0.f;
  }
  if (tid < 128) {
    s_xp[(tid + 1) * LROW + 3] = 0.f;
    s_xp[(tid + 1) * LROW + 132] = 0.f;
  }

  float st_s[3], st_q[3];

  #pragma unroll
  for (int c = 0; c < 3; c++) {
    if (c) __syncthreads();  // previous channel's compute must finish before restage

    // ---- stage plane (b,c), accumulating stats from the loaded registers ----
    const float4* xp = (const float4*)(x + ((size_t)b * 3 + c) * 16384);
    float s = 0.f, q = 0.f;
    #pragma unroll
    for (int i = 0; i < 16; i++) {
      float4 a4 = xp[i * 256 + tid];
      int idx = (i * 256 + tid) << 2;      // flat elem index in 128x128 plane
      int r = idx >> 7, col = idx & 127;
      float* d = &s_xp[(r + 1) * LROW + col + 4];
      d[0] = a4.x; d[1] = a4.y; d[2] = a4.z; d[3] = a4.w;
      s += (a4.x + a4.y) + (a4.z + a4.w);
      q += (a4.x * a4.x + a4.y * a4.y) + (a4.z * a4.z + a4.w * a4.w);
    }
    st_s[c] = s; st_q[c] = q;
    __syncthreads();

    // ---- 25-tap conv partials for this channel, 3 positions per thread ----
    #pragma unroll
    for (int pp = 0; pp < 3; pp++) {
      int pos = tid + pp * 256;
      if (pos < 676) {
        int oy = pos / 26, ox = pos - oy * 26;
        // window rows r0..r0+4 (r0=5oy-1) -> LDS rows 5oy..; cols c0..c0+4 -> 5ox+3..
        const float* base = &s_xp[(5 * oy) * LROW + 5 * ox + 3];
        float a0 = 0.f, a1 = 0.f, a2 = 0.f;
        #pragma unroll
        for (int ky = 0; ky < 5; ky++) {
          #pragma unroll
          for (int kx = 0; kx < 5; kx++) {
            float v = base[ky * LROW + kx];          // ds_read, imm offset
            a0 += w1g[0 * 75 + c * 25 + ky * 5 + kx] * v;  // uniform -> s_load
            a1 += w1g[1 * 75 + c * 25 + ky * 5 + kx] * v;
            a2 += w1g[2 * 75 + c * 25 + ky * 5 + kx] * v;
          }
        }
        size_t gp = (size_t)b * 676 + pos;
        S[(size_t)(c * 3 + 0) * NPOS + gp] = a0;
        S[(size_t)(c * 3 + 1) * NPOS + gp] = a1;
        S[(size_t)(c * 3 + 2) * NPOS + gp] = a2;
      }
    }
  }

  // ---- block-reduce stats (6 scalars) -> psumS[ch][b] ----
  #pragma unroll
  for (int off = 32; off; off >>= 1) {
    #pragma unroll
    for (int c = 0; c < 3; c++) {
      st_s[c] += __shfl_down(st_s[c], off);
      st_q[c] += __shfl_down(st_q[c], off);
    }
  }
  __syncthreads();  // s_xp reads done; reuse barrier before red writes is fine
  int lane = tid & 63, wv = tid >> 6;
  if (lane == 0) {
    red[wv][0] = st_s[0]; red[wv][1] = st_s[1]; red[wv][2] = st_s[2];
    red[wv][3] = st_q[0]; red[wv][4] = st_q[1]; red[wv][5] = st_q[2];
  }
  __syncthreads();
  if (tid < 6)
    psumS[tid * 512 + b] = (red[0][tid] + red[1][tid]) + (red[2][tid] + red[3][tid]);
}

// ---------------- K1b: fold 512 partials -> 6 stats ----------------
__global__ __launch_bounds__(384) void k_reduce(const float* __restrict__ psumS,
                                                float* __restrict__ stats) {
  int w = threadIdx.x >> 6, lane = threadIdx.x & 63;
  const float* src = psumS + w * 512;
  float acc = 0.f;
  #pragma unroll
  for (int k = 0; k < 8; k++) acc += src[lane + 64 * k];
  #pragma unroll
  for (int off = 32; off; off >>= 1) acc += __shfl_down(acc, off);
  if (lane == 0) stats[w] = acc;
}

// ---------------- Kg: gather live fc1 columns -> bf16 B-fragment layout ----------------
__device__ inline float gval(const float* __restrict__ row, int k) {
  if (k >= 2028) return 0.f;
  int c = k / 676;
  int rem = k - c * 676;
  int oy = rem / 26, ox = rem - oy * 26;
  int col = c * 4225 + ((5 * oy) >> 1) * 65 + ((5 * ox) >> 1);
  return row[col];
}

__global__ __launch_bounds__(256) void k_gather(const float* __restrict__ fc1_w,
                                                ushort* __restrict__ WgtB) {
  int gid = blockIdx.x * 256 + threadIdx.x;  // 32768 total
  int l = gid & 63;
  int n = ((gid >> 12) << 4) + (l & 15);
  int kbase = (((gid >> 6) & 63) << 5) + ((l >> 4) << 3);
  const float* row = fc1_w + n * 12675;
  uint4 o;
  unsigned int w[4];
  #pragma unroll
  for (int i = 0; i < 4; i++) {
    ushort lo = f2bf(gval(row, kbase + 2 * i));
    ushort hi = f2bf(gval(row, kbase + 2 * i + 1));
    w[i] = (unsigned int)lo | ((unsigned int)hi << 16);
  }
  o.x = w[0]; o.y = w[1]; o.z = w[2]; o.w = w[3];
  ((uint4*)WgtB)[gid] = o;
}

// ---------------- K2: combine S + stats -> BN'd conv1 + relu + 1x1 conv2 + relu -> bf16 feat ----
__global__ __launch_bounds__(256) void k_combine(
    const float* __restrict__ S,       // [9][NPOS]
    const float* __restrict__ stats,
    const float* __restrict__ gamma, const float* __restrict__ beta,
    const float* __restrict__ w1, const float* __restrict__ b1,
    const float* __restrict__ w2, const float* __restrict__ b2,
    ushort* __restrict__ featB)        // [512][2048] bf16
{
  __shared__ float s_w1[225];
  __shared__ float s_w2[9];
  __shared__ float s_scale[3], s_shift[3], s_b1[3], s_b2[3];
  __shared__ float s_T[9][9];          // [rcl*3+ccl][o*3+c]
  const int tid = threadIdx.x;
  if (tid < 225) s_w1[tid] = w1[tid];
  if (tid < 9) s_w2[tid] = w2[tid * 25];
  if (tid < 3) {
    const float N = 512.f * 128.f * 128.f;
    float mean = stats[tid] / N;
    float var = stats[3 + tid] / N - mean * mean;
    float sc = gamma[tid] * rsqrtf(var + BN_EPS);
    s_scale[tid] = sc;
    s_shift[tid] = beta[tid] - mean * sc;
    s_b1[tid] = b1[tid];
    s_b2[tid] = b2[tid];
  }
  __syncthreads();
  if (tid < 81) {
    int cls = tid / 9, oc = tid - (tid / 9) * 9;
    int rcl = cls / 3, ccl = cls - rcl * 3;
    int o = oc / 3, c = oc - o * 3;
    int ky0 = (rcl == 0) ? 1 : 0, ky1 = (rcl == 2) ? 3 : 4;
    int kx0 = (ccl == 0) ? 1 : 0, kx1 = (ccl == 2) ? 3 : 4;
    float t = 0.f;
    for (int ky = ky0; ky <= ky1; ky++)
      for (int kx = kx0; kx <= kx1; kx++)
        t += s_w1[o * 75 + c * 25 + ky * 5 + kx];
    s_T[cls][oc] = t;
  }
  __syncthreads();

  int gpos = blockIdx.x * 256 + tid;
  int b = gpos / 676;
  int pos = gpos - b * 676;
  int oy = pos / 26, ox = pos - oy * 26;
  int rcl = (oy == 0) ? 0 : ((oy == 25) ? 2 : 1);
  int ccl = (ox == 0) ? 0 : ((ox == 25) ? 2 : 1);
  int cls = rcl * 3 + ccl;

  float h[3];
  #pragma unroll
  for (int o = 0; o < 3; o++) {
    float a = s_b1[o];
    #pragma unroll
    for (int c = 0; c < 3; c++) {
      a += s_scale[c] * S[(size_t)(c * 3 + o) * NPOS + gpos];
      a += s_shift[c] * s_T[cls][o * 3 + c];
    }
    h[o] = fmaxf(a, 0.f);
  }
  ushort* fb = featB + (size_t)b * 2048;
  #pragma unroll
  for (int o = 0; o < 3; o++) {
    float v = s_b2[o] + s_w2[3 * o] * h[0] + s_w2[3 * o + 1] * h[1] + s_w2[3 * o + 2] * h[2];
    fb[o * 676 + pos] = f2bf(fmaxf(v, 0.f));
  }
  if (pos < 20) fb[2028 + pos] = 0;  // zero K-pad
}

// ---------------- K3: fc1 via MFMA + relu + fc2 + log_softmax ----------------
__global__ __launch_bounds__(512) void k_fc(
    const ushort* __restrict__ featB,  // [512][2048] bf16
    const ushort* __restrict__ WgtB,   // B-fragment layout
    const float* __restrict__ fc1_b,
    const float* __restrict__ fc2_w, const float* __restrict__ fc2_b,
    float* __restrict__ out)           // [512,10]
{
  __shared__ float s_f[16][132];
  __shared__ float s_lg[16][10];
  const int tid = threadIdx.x;
  const int lane = tid & 63;
  const int t = tid >> 6;           // N-tile 0..7
  const int m0 = blockIdx.x * 16;

  const ushort* aptr = featB + (size_t)(m0 + (lane & 15)) * 2048 + ((lane >> 4) << 3);
  const ushort* bptr = WgtB + ((size_t)t * 4096 + lane) * 8;

  f32x4 acc = {0.f, 0.f, 0.f, 0.f};
  #pragma unroll 4
  for (int kk = 0; kk < 64; kk++) {
    short8 a = *(const short8*)(aptr + kk * 32);
    short8 bfr = *(const short8*)(bptr + kk * 512);
    acc = __builtin_amdgcn_mfma_f32_16x16x32_bf16(a, bfr, acc, 0, 0, 0);
  }
  {
    int n = t * 16 + (lane & 15);
    float bias = fc1_b[n];
    int mb = (lane >> 4) << 2;
    #pragma unroll
    for (int r = 0; r < 4; r++)
      s_f[mb + r][n] = fmaxf(acc[r] + bias, 0.f);
  }
  __syncthreads();

  if (tid < 160) {
    int m = tid & 15, q = tid >> 4;
    const float* wr = fc2_w + q * 128;
    float a2 = fc2_b[q];
    #pragma unroll 8
    for (int k = 0; k < 128; k++) a2 += wr[k] * s_f[m][k];
    s_lg[m][q] = a2;
  }
  __syncthreads();

  if (tid < 16) {
    float mx = s_lg[tid][0];
    #pragma unroll
    for (int q = 1; q < 10; q++) mx = fmaxf(mx, s_lg[tid][q]);
    float se = 0.f;
    #pragma unroll
    for (int q = 0; q < 10; q++) se += expf(s_lg[tid][q] - mx);
    float lse = mx + logf(se);
    float* op = out + (size_t)(m0 + tid) * 10;
    #pragma unroll
    for (int q = 0; q < 10; q++) op[q] = s_lg[tid][q] - lse;
  }
}

extern "C" void kernel_launch(void* const* d_in, const int* in_sizes, int n_in,
                              void* d_out, int out_size, void* d_ws, size_t ws_size,
                              hipStream_t stream) {
  const float* x      = (const float*)d_in[0];
  const float* gamma  = (const float*)d_in[1];
  const float* beta   = (const float*)d_in[2];
  const float* w1     = (const float*)d_in[3];
  const float* b1     = (const float*)d_in[4];
  const float* w2     = (const float*)d_in[5];
  const float* b2     = (const float*)d_in[6];
  const float* fc1_w  = (const float*)d_in[7];
  const float* fc1_b  = (const float*)d_in[8];
  const float* fc2_w  = (const float*)d_in[9];
  const float* fc2_b  = (const float*)d_in[10];
  float* out = (float*)d_out;
  float* wsf = (float*)d_ws;

  float* stats  = wsf;                      // [0..5]
  float* psumS  = wsf + 64;                 // [6][512]
  ushort* WgtB  = (ushort*)(wsf + 16384);   // 512 KB bf16
  ushort* featB = (ushort*)(wsf + 262144);  // 2 MB bf16
  float* S      = wsf + 786432;             // [9][NPOS] = 12.5 MB

  k_convraw<<<512, 256, 0, stream>>>(x, w1, S, psumS);
  k_gather<<<128, 256, 0, stream>>>(fc1_w, WgtB);
  k_reduce<<<1, 384, 0, stream>>>(psumS, stats);
  k_combine<<<1352, 256, 0, stream>>>(S, stats, gamma, beta, w1, b1, w2, b2, featB);
  k_fc<<<32, 512, 0, stream>>>(featB, WgtB, fc1_b, fc2_w, fc2_b, out);
}

// Round 7
// 56.804 us; speedup vs baseline: 5.3325x; 1.0575x over previous
//
#include <hip/hip_runtime.h>

#define BN_EPS 1e-5f

typedef short short8 __attribute__((ext_vector_type(8)));
typedef float f32x4 __attribute__((ext_vector_type(4)));
typedef unsigned short ushort;

__device__ inline ushort f2bf(float f) {
  unsigned int u = __float_as_uint(f);
  u += 0x7FFFu + ((u >> 16) & 1u);
  return (ushort)(u >> 16);
}

// ws float-word layout:
//   [0..5]         stats (3 sums, 3 sumsqs)
//   [64..6207]     psumS [6][1024]  (per (b,half) per-channel partials)
//   [16384..]      WgtB  bf16 [8][64][64][8]   (512 KB = 131072 words)
//   [262144..]     featB bf16 [512][2048]      (2 MB  = 524288 words)
//   [786432..]     S     [9][346112] fp32 raw conv partials (12.5 MB)

#define NPOS 346112  // 512*676
#define LROW 144     // padded LDS row stride

// ---------------- K1: LDS-staged x pass -> raw conv partials S + stats ----------------
// Block = (b, c, half): 3072 blocks. Stages 64 real rows + 1 zero pad row (37.4 KB),
// computes 13 output rows x 26 cols of the 3 per-channel conv partials.
__global__ __launch_bounds__(256) void k_convraw(
    const float* __restrict__ x,       // [512,3,128,128]
    const float* __restrict__ w1g,     // [3,3,5,5] uniform (SGPR) loads
    float* __restrict__ S,             // [9][NPOS]
    float* __restrict__ psumS)         // [6][1024]
{
  __shared__ float s_xp[65 * LROW];
  __shared__ float red[4][2];
  const int tid = threadIdx.x;
  const int bid = blockIdx.x;          // b*6 + c*2 + h
  const int h = bid & 1;
  const int c = (bid >> 1) % 3;
  const int b = bid / 6;

  // zero pads: one pad row (input row -1 for h=0, row 128 for h=1) + cols 3/132 all rows
  const int zrow = h ? 64 : 0;
  for (int i = tid; i < LROW; i += 256) s_xp[zrow * LROW + i] = 0.f;
  if (tid < 65) { s_xp[tid * LROW + 3] = 0.f; s_xp[tid * LROW + 132] = 0.f; }

  const int r0 = h ? 64 : 0;           // first real input row staged
  const int off0 = h ? 0 : 1;          // LDS row = (r - r0) + off0

  // ---- stage 64 rows (8 float4 per thread), stats from the same registers ----
  const float4* xp = (const float4*)(x + ((size_t)b * 3 + c) * 16384 + (size_t)r0 * 128);
  float s = 0.f, q = 0.f;
  #pragma unroll
  for (int i = 0; i < 8; i++) {
    int v = i * 256 + tid;             // 0..2047
    float4 a4 = xp[v];
    int lr = (v >> 5) + off0;
    int col = (v & 31) << 2;
    float* d = &s_xp[lr * LROW + col + 4];
    d[0] = a4.x; d[1] = a4.y; d[2] = a4.z; d[3] = a4.w;
    s += (a4.x + a4.y) + (a4.z + a4.w);
    q += (a4.x * a4.x + a4.y * a4.y) + (a4.z * a4.z + a4.w * a4.w);
  }
  __syncthreads();

  // ---- 25-tap conv partials, 338 positions, weights via uniform s_loads ----
  const float* wc = w1g + c * 25;
  #pragma unroll
  for (int pp = 0; pp < 2; pp++) {
    int p = tid + pp * 256;
    if (p < 338) {
      int ol = p / 26, ox = p - ol * 26;
      const float* base = &s_xp[(5 * ol) * LROW + 5 * ox + 3];
      float a0 = 0.f, a1 = 0.f, a2 = 0.f;
      #pragma unroll
      for (int ky = 0; ky < 5; ky++) {
        #pragma unroll
        for (int kx = 0; kx < 5; kx++) {
          float v = base[ky * LROW + kx];    // ds_read, imm offset
          a0 += wc[ky * 5 + kx] * v;         // SGPR operand
          a1 += wc[75 + ky * 5 + kx] * v;
          a2 += wc[150 + ky * 5 + kx] * v;
        }
      }
      int oy = h * 13 + ol;
      size_t gp = (size_t)b * 676 + oy * 26 + ox;
      S[(size_t)(c * 3 + 0) * NPOS + gp] = a0;
      S[(size_t)(c * 3 + 1) * NPOS + gp] = a1;
      S[(size_t)(c * 3 + 2) * NPOS + gp] = a2;
    }
  }

  // ---- block-reduce stats -> psumS ----
  #pragma unroll
  for (int off = 32; off; off >>= 1) {
    s += __shfl_down(s, off);
    q += __shfl_down(q, off);
  }
  int lane = tid & 63, wv = tid >> 6;
  if (lane == 0) { red[wv][0] = s; red[wv][1] = q; }
  __syncthreads();
  if (tid == 0)
    psumS[c * 1024 + b * 2 + h] = (red[0][0] + red[1][0]) + (red[2][0] + red[3][0]);
  if (tid == 1)
    psumS[(3 + c) * 1024 + b * 2 + h] = (red[0][1] + red[1][1]) + (red[2][1] + red[3][1]);
}

// ---------------- K1b: fold 1024 partials x 6 -> 6 stats ----------------
__global__ __launch_bounds__(384) void k_reduce(const float* __restrict__ psumS,
                                                float* __restrict__ stats) {
  int w = threadIdx.x >> 6, lane = threadIdx.x & 63;
  const float* src = psumS + w * 1024;
  float acc = 0.f;
  #pragma unroll
  for (int k = 0; k < 16; k++) acc += src[lane + 64 * k];
  #pragma unroll
  for (int off = 32; off; off >>= 1) acc += __shfl_down(acc, off);
  if (lane == 0) stats[w] = acc;
}

// ---------------- Kg: gather live fc1 columns -> bf16 B-fragment layout ----------------
__device__ inline float gval(const float* __restrict__ row, int k) {
  if (k >= 2028) return 0.f;
  int c = k / 676;
  int rem = k - c * 676;
  int oy = rem / 26, ox = rem - oy * 26;
  int col = c * 4225 + ((5 * oy) >> 1) * 65 + ((5 * ox) >> 1);
  return row[col];
}

__global__ __launch_bounds__(256) void k_gather(const float* __restrict__ fc1_w,
                                                ushort* __restrict__ WgtB) {
  int gid = blockIdx.x * 256 + threadIdx.x;  // 32768 total
  int l = gid & 63;
  int n = ((gid >> 12) << 4) + (l & 15);
  int kbase = (((gid >> 6) & 63) << 5) + ((l >> 4) << 3);
  const float* row = fc1_w + n * 12675;
  uint4 o;
  unsigned int w[4];
  #pragma unroll
  for (int i = 0; i < 4; i++) {
    ushort lo = f2bf(gval(row, kbase + 2 * i));
    ushort hi = f2bf(gval(row, kbase + 2 * i + 1));
    w[i] = (unsigned int)lo | ((unsigned int)hi << 16);
  }
  o.x = w[0]; o.y = w[1]; o.z = w[2]; o.w = w[3];
  ((uint4*)WgtB)[gid] = o;
}

// ---------------- K2: combine S + stats -> BN'd conv1 + relu + 1x1 conv2 + relu -> bf16 feat ----
__global__ __launch_bounds__(256) void k_combine(
    const float* __restrict__ S,       // [9][NPOS]
    const float* __restrict__ stats,
    const float* __restrict__ gamma, const float* __restrict__ beta,
    const float* __restrict__ w1, const float* __restrict__ b1,
    const float* __restrict__ w2, const float* __restrict__ b2,
    ushort* __restrict__ featB)        // [512][2048] bf16
{
  __shared__ float s_w1[225];
  __shared__ float s_w2[9];
  __shared__ float s_scale[3], s_shift[3], s_b1[3], s_b2[3];
  __shared__ float s_T[9][9];          // [rcl*3+ccl][o*3+c]
  const int tid = threadIdx.x;
  if (tid < 225) s_w1[tid] = w1[tid];
  if (tid < 9) s_w2[tid] = w2[tid * 25];
  if (tid < 3) {
    const float N = 512.f * 128.f * 128.f;
    float mean = stats[tid] / N;
    float var = stats[3 + tid] / N - mean * mean;
    float sc = gamma[tid] * rsqrtf(var + BN_EPS);
    s_scale[tid] = sc;
    s_shift[tid] = beta[tid] - mean * sc;
    s_b1[tid] = b1[tid];
    s_b2[tid] = b2[tid];
  }
  __syncthreads();
  if (tid < 81) {
    int cls = tid / 9, oc = tid - (tid / 9) * 9;
    int rcl = cls / 3, ccl = cls - rcl * 3;
    int o = oc / 3, c = oc - o * 3;
    int ky0 = (rcl == 0) ? 1 : 0, ky1 = (rcl == 2) ? 3 : 4;
    int kx0 = (ccl == 0) ? 1 : 0, kx1 = (ccl == 2) ? 3 : 4;
    float t = 0.f;
    for (int ky = ky0; ky <= ky1; ky++)
      for (int kx = kx0; kx <= kx1; kx++)
        t += s_w1[o * 75 + c * 25 + ky * 5 + kx];
    s_T[cls][oc] = t;
  }
  __syncthreads();

  int gpos = blockIdx.x * 256 + tid;
  int b = gpos / 676;
  int pos = gpos - b * 676;
  int oy = pos / 26, ox = pos - oy * 26;
  int rcl = (oy == 0) ? 0 : ((oy == 25) ? 2 : 1);
  int ccl = (ox == 0) ? 0 : ((ox == 25) ? 2 : 1);
  int cls = rcl * 3 + ccl;

  float h[3];
  #pragma unroll
  for (int o = 0; o < 3; o++) {
    float a = s_b1[o];
    #pragma unroll
    for (int c = 0; c < 3; c++) {
      a += s_scale[c] * S[(size_t)(c * 3 + o) * NPOS + gpos];
      a += s_shift[c] * s_T[cls][o * 3 + c];
    }
    h[o] = fmaxf(a, 0.f);
  }
  ushort* fb = featB + (size_t)b * 2048;
  #pragma unroll
  for (int o = 0; o < 3; o++) {
    float v = s_b2[o] + s_w2[3 * o] * h[0] + s_w2[3 * o + 1] * h[1] + s_w2[3 * o + 2] * h[2];
    fb[o * 676 + pos] = f2bf(fmaxf(v, 0.f));
  }
  if (pos < 20) fb[2028 + pos] = 0;  // zero K-pad
}

// ---------------- K3: fc1 via MFMA + relu + fc2 + log_softmax ----------------
__global__ __launch_bounds__(512) void k_fc(
    const ushort* __restrict__ featB,  // [512][2048] bf16
    const ushort* __restrict__ WgtB,   // B-fragment layout
    const float* __restrict__ fc1_b,
    const float* __restrict__ fc2_w, const float* __restrict__ fc2_b,
    float* __restrict__ out)           // [512,10]
{
  __shared__ float s_f[16][132];
  __shared__ float s_lg[16][10];
  const int tid = threadIdx.x;
  const int lane = tid & 63;
  const int t = tid >> 6;           // N-tile 0..7
  const int m0 = blockIdx.x * 16;

  const ushort* aptr = featB + (size_t)(m0 + (lane & 15)) * 2048 + ((lane >> 4) << 3);
  const ushort* bptr = WgtB + ((size_t)t * 4096 + lane) * 8;

  f32x4 acc = {0.f, 0.f, 0.f, 0.f};
  #pragma unroll 4
  for (int kk = 0; kk < 64; kk++) {
    short8 a = *(const short8*)(aptr + kk * 32);
    short8 bfr = *(const short8*)(bptr + kk * 512);
    acc = __builtin_amdgcn_mfma_f32_16x16x32_bf16(a, bfr, acc, 0, 0, 0);
  }
  {
    int n = t * 16 + (lane & 15);
    float bias = fc1_b[n];
    int mb = (lane >> 4) << 2;
    #pragma unroll
    for (int r = 0; r < 4; r++)
      s_f[mb + r][n] = fmaxf(acc[r] + bias, 0.f);
  }
  __syncthreads();

  if (tid < 160) {
    int m = tid & 15, q = tid >> 4;
    const float* wr = fc2_w + q * 128;
    float a2 = fc2_b[q];
    #pragma unroll 8
    for (int k = 0; k < 128; k++) a2 += wr[k] * s_f[m][k];
    s_lg[m][q] = a2;
  }
  __syncthreads();

  if (tid < 16) {
    float mx = s_lg[tid][0];
    #pragma unroll
    for (int q = 1; q < 10; q++) mx = fmaxf(mx, s_lg[tid][q]);
    float se = 0.f;
    #pragma unroll
    for (int q = 0; q < 10; q++) se += expf(s_lg[tid][q] - mx);
    float lse = mx + logf(se);
    float* op = out + (size_t)(m0 + tid) * 10;
    #pragma unroll
    for (int q = 0; q < 10; q++) op[q] = s_lg[tid][q] - lse;
  }
}

extern "C" void kernel_launch(void* const* d_in, const int* in_sizes, int n_in,
                              void* d_out, int out_size, void* d_ws, size_t ws_size,
                              hipStream_t stream) {
  const float* x      = (const float*)d_in[0];
  const float* gamma  = (const float*)d_in[1];
  const float* beta   = (const float*)d_in[2];
  const float* w1     = (const float*)d_in[3];
  const float* b1     = (const float*)d_in[4];
  const float* w2     = (const float*)d_in[5];
  const float* b2     = (const float*)d_in[6];
  const float* fc1_w  = (const float*)d_in[7];
  const float* fc1_b  = (const float*)d_in[8];
  const float* fc2_w  = (const float*)d_in[9];
  const float* fc2_b  = (const float*)d_in[10];
  float* out = (float*)d_out;
  float* wsf = (float*)d_ws;

  float* stats  = wsf;                      // [0..5]
  float* psumS  = wsf + 64;                 // [6][1024]
  ushort* WgtB  = (ushort*)(wsf + 16384);   // 512 KB bf16
  ushort* featB = (ushort*)(wsf + 262144);  // 2 MB bf16
  float* S      = wsf + 786432;             // [9][NPOS] = 12.5 MB

  k_convraw<<<3072, 256, 0, stream>>>(x, w1, S, psumS);
  k_gather<<<128, 256, 0, stream>>>(fc1_w, WgtB);
  k_reduce<<<1, 384, 0, stream>>>(psumS, stats);
  k_combine<<<1352, 256, 0, stream>>>(S, stats, gamma, beta, w1, b1, w2, b2, featB);
  k_fc<<<32, 512, 0, stream>>>(featB, WgtB, fc1_b, fc2_w, fc2_b, out);
}